// Round 1
// baseline (788.467 us; speedup 1.0000x reference)
//
#include <hip/hip_runtime.h>
#include <hip/hip_bf16.h>
#include <stdint.h>

#define TWO_N  8192
#define NHALF  4096
#define DDIM   256
#define MARGIN 0.5f

// ---- workspace layout (bytes) ----
static const size_t OFF_EMB  = 0;                            // 8192*256 bf16 = 4 MB
static const size_t OFF_X2   = 4u * 1024 * 1024;             // 8192 f32
static const size_t OFF_AP   = OFF_X2 + (size_t)TWO_N * 4;   // 4096 f32
static const size_t OFF_FLAG = OFF_AP + (size_t)NHALF * 4;   // 1 int (padded)
static const size_t OFF_PART = OFF_FLAG + 256;               // 64 * 8192 f32 = 2 MB
static const size_t OFF_RS   = OFF_PART + 64ull * TWO_N * 4; // 8192 f32

typedef __attribute__((ext_vector_type(8))) short bf16x8;
typedef __attribute__((ext_vector_type(4))) float f32x4;

__device__ inline ushort f2bf(float f) {
  uint32_t u = __float_as_uint(f);
  uint32_t r = (u + 0x7FFFu + ((u >> 16) & 1u)) >> 16;  // RNE
  return (ushort)r;
}
__device__ inline float bf2f(ushort h) { return __uint_as_float((uint32_t)h << 16); }

// async global->LDS, 16B per lane; LDS dest = wave-uniform base + lane*16
__device__ inline void gload_lds16(const void* g, void* l) {
  __builtin_amdgcn_global_load_lds(
      (const __attribute__((address_space(1))) uint32_t*)(uintptr_t)g,
      (__attribute__((address_space(3))) uint32_t*)(uint32_t)(uintptr_t)l,
      16, 0, 0);
}

// ---------------- prep: bf16 convert + x2 (from bf16 values) + mask-dtype detect ----------------
__global__ __launch_bounds__(256) void smv2_prep(
    const float* __restrict__ emb,
    const uint32_t* __restrict__ maskw,
    ushort* __restrict__ emb_bf,
    float* __restrict__ x2,
    int* __restrict__ flag)
{
  const int t = threadIdx.x;
  if (blockIdx.x == 0) {
    __shared__ int sflag;
    if (t == 0) sflag = 0;
    __syncthreads();
    int found = 0;
    #pragma unroll
    for (int k = 0; k < 8; ++k) {
      uint32_t w = maskw[t * 8 + k];
      // bytes all in {0,1} and value > 1  => 1-byte-per-element mask
      if (w > 1u && (w & 0xFEFEFEFEu) == 0u) found = 1;
    }
    if (found) atomicOr(&sflag, 1);
    __syncthreads();
    if (t == 0) *flag = sflag;
  }
  const int row  = blockIdx.x * 8 + (t >> 5);
  const int lane = t & 31;
  const float* rp = emb + (size_t)row * DDIM + lane * 8;
  float4 v0 = *(const float4*)(rp);
  float4 v1 = *(const float4*)(rp + 4);
  float vals[8] = {v0.x, v0.y, v0.z, v0.w, v1.x, v1.y, v1.z, v1.w};
  uint32_t packed[4];
  float ss = 0.f;
  #pragma unroll
  for (int k = 0; k < 4; ++k) {
    ushort h0 = f2bf(vals[2 * k]);
    ushort h1 = f2bf(vals[2 * k + 1]);
    packed[k] = (uint32_t)h0 | ((uint32_t)h1 << 16);
    float f0 = bf2f(h0), f1 = bf2f(h1);
    ss += f0 * f0 + f1 * f1;
  }
  *(uint4*)(emb_bf + (size_t)row * DDIM + lane * 8) =
      make_uint4(packed[0], packed[1], packed[2], packed[3]);
  #pragma unroll
  for (int m = 1; m < 32; m <<= 1) ss += __shfl_xor(ss, m);
  if (lane == 0) x2[row] = ss;
}

// ---------------- main: fused Gram -> distance -> exp -> masked row partials ----------------
__global__ __launch_bounds__(256, 1) void smv2_main(
    const ushort* __restrict__ emb_bf,
    const float* __restrict__ x2,
    const uint8_t* __restrict__ mask8,
    const int* __restrict__ flagp,
    float* __restrict__ ap,
    float* __restrict__ partial)
{
  __shared__ char ldsA[128 * 512];
  __shared__ char ldsB[128 * 512];

  const int t  = threadIdx.x;
  const int l  = t & 63;
  const int w  = t >> 6;
  const int bx = blockIdx.x;
  const int by = blockIdx.y;
  const int brow = by * 128;
  const int bcol = bx * 128;

  // stage A (rows) and B (cols) panels: 128 x 256 bf16 each, XOR-swizzled.
  // LDS[row][c] = G[row][c ^ ((row&7)<<4)]  (pre-swizzled global source, linear LDS dest)
  const char* gA = (const char*)(emb_bf + (size_t)brow * DDIM);
  const char* gB = (const char*)(emb_bf + (size_t)bcol * DDIM);
  #pragma unroll
  for (int r = 0; r < 16; ++r) {
    const int dl  = r * 4096 + w * 1024 + l * 16;  // linear LDS byte offset
    const int row = dl >> 9;
    const int c   = dl & 511;
    const int cb  = c ^ ((row & 7) << 4);
    gload_lds16(gA + (size_t)row * 512 + cb, ldsA + dl);
    gload_lds16(gB + (size_t)row * 512 + cb, ldsB + dl);
  }
  __syncthreads();  // compiler drains vmcnt before s_barrier

  const int wr = w >> 1;           // wave row 0..1  (64-row half)
  const int wc = w & 1;            // wave col 0..1  (64-col half)
  const int cl = l & 15;           // fragment row/col lane
  const int kh = l >> 4;           // k-block 0..3
  const int swz = (cl & 7) << 4;

  f32x4 acc[4][4];
  #pragma unroll
  for (int m = 0; m < 4; ++m)
    #pragma unroll
    for (int n = 0; n < 4; ++n) {
      f32x4 z = {0.f, 0.f, 0.f, 0.f};
      acc[m][n] = z;
    }

  #pragma unroll
  for (int ks = 0; ks < 8; ++ks) {
    const int kb = ks * 64 + kh * 16;   // byte offset of this lane's 8 bf16 k-elements
    bf16x8 a[4], b[4];
    #pragma unroll
    for (int m = 0; m < 4; ++m) {
      a[m] = *(const bf16x8*)(ldsA + (wr * 64 + m * 16 + cl) * 512 + (kb ^ swz));
      b[m] = *(const bf16x8*)(ldsB + (wc * 64 + m * 16 + cl) * 512 + (kb ^ swz));
    }
    #pragma unroll
    for (int m = 0; m < 4; ++m)
      #pragma unroll
      for (int n = 0; n < 4; ++n)
        acc[m][n] = __builtin_amdgcn_mfma_f32_16x16x32_bf16(a[m], b[n], acc[m][n], 0, 0, 0);
  }

  __syncthreads();                 // done with LDS tiles; reuse ldsA for row partials
  float* part = (float*)ldsA;      // [2][128]

  const int isByte = *flagp;
  const uint32_t* maskww = (const uint32_t*)mask8;

  #pragma unroll
  for (int m = 0; m < 4; ++m) {
    #pragma unroll
    for (int q = 0; q < 4; ++q) {
      const int lrow = wr * 64 + m * 16 + kh * 4 + q;  // C/D: row = (l>>4)*4 + reg
      const int gi = brow + lrow;
      const float xi = x2[gi];
      float rp = 0.f;
      #pragma unroll
      for (int n = 0; n < 4; ++n) {
        const int gj = bcol + wc * 64 + n * 16 + cl;   // C/D: col = l&15
        const float g = acc[m][n][q];
        float sq = (gi == gj) ? 0.f : (xi + x2[gj] - 2.f * g);
        sq = fmaxf(sq, 0.f) + 1e-12f;
        const float dd = sqrtf(sq);
        if (gj == gi + NHALF && gi < NHALF) ap[gi] = dd;  // anchor-positive distance
        const size_t idx = (size_t)gi * TWO_N + gj;
        const bool mk = isByte ? (mask8[idx] != 0) : (maskww[idx] != 0u);
        rp += mk ? __expf(MARGIN - dd) : 0.f;
      }
      // reduce over the 16 lanes covering this row's 16 cols (x4 n-frags = 64 cols)
      #pragma unroll
      for (int s = 1; s < 16; s <<= 1) rp += __shfl_xor(rp, s);
      if (cl == 0) part[wc * 128 + lrow] = rp;
    }
  }
  __syncthreads();
  if (t < 128) {
    partial[(size_t)bx * TWO_N + brow + t] = part[t] + part[128 + t];
  }
}

// ---------------- row sums: rs[i] = sum over 64 col-tiles ----------------
__global__ __launch_bounds__(256) void smv2_rowsum(
    const float* __restrict__ partial, float* __restrict__ rs)
{
  const int row = blockIdx.x * 256 + threadIdx.x;
  float s = 0.f;
  #pragma unroll 8
  for (int b = 0; b < 64; ++b) s += partial[(size_t)b * TWO_N + row];
  rs[row] = s;
}

// ---------------- finalize: j = log(rs[i]+rs[i+N]) + ap[i]; loss ----------------
__global__ __launch_bounds__(1024) void smv2_finalize(
    const float* __restrict__ rs, const float* __restrict__ ap,
    float* __restrict__ out)
{
  const int t = threadIdx.x;
  float sum = 0.f, cnt = 0.f;
  for (int i = t; i < NHALF; i += 1024) {
    float rsum = rs[i] + rs[i + NHALF];
    float jv = logf(rsum) + ap[i];
    if (!isnan(jv)) {
      cnt += 1.f;
      float mj = fmaxf(jv, 0.f);
      sum += mj * mj;
    }
  }
  __shared__ float ssum[16], scnt[16];
  #pragma unroll
  for (int s = 32; s >= 1; s >>= 1) {
    sum += __shfl_down(sum, s);
    cnt += __shfl_down(cnt, s);
  }
  const int wid = t >> 6, lid = t & 63;
  if (lid == 0) { ssum[wid] = sum; scnt[wid] = cnt; }
  __syncthreads();
  if (t == 0) {
    float S = 0.f, C = 0.f;
    #pragma unroll
    for (int i = 0; i < 16; ++i) { S += ssum[i]; C += scnt[i]; }
    if (C < 1.f) C = 1.f;
    out[0] = S / C * 0.5f;
  }
}

extern "C" void kernel_launch(void* const* d_in, const int* in_sizes, int n_in,
                              void* d_out, int out_size, void* d_ws, size_t ws_size,
                              hipStream_t stream) {
  const float* emb = (const float*)d_in[0];
  const void* mask = d_in[1];
  char* ws = (char*)d_ws;

  ushort* emb_bf = (ushort*)(ws + OFF_EMB);
  float*  x2     = (float*)(ws + OFF_X2);
  float*  ap     = (float*)(ws + OFF_AP);
  int*    flag   = (int*)(ws + OFF_FLAG);
  float*  part   = (float*)(ws + OFF_PART);
  float*  rs     = (float*)(ws + OFF_RS);

  smv2_prep<<<1024, 256, 0, stream>>>(emb, (const uint32_t*)mask, emb_bf, x2, flag);
  dim3 grid(64, 64);
  smv2_main<<<grid, 256, 0, stream>>>(emb_bf, x2, (const uint8_t*)mask, flag, ap, part);
  smv2_rowsum<<<32, 256, 0, stream>>>(part, rs);
  smv2_finalize<<<1, 1024, 0, stream>>>(rs, ap, (float*)d_out);
}

// Round 2
// 517.282 us; speedup vs baseline: 1.5243x; 1.5243x over previous
//
#include <hip/hip_runtime.h>
#include <hip/hip_bf16.h>
#include <stdint.h>

#define TWO_N  8192
#define NHALF  4096
#define DDIM   256
#define MARGIN 0.5f

// ---- workspace layout (bytes) ----
static const size_t OFF_EMB  = 0;                            // 8192*256 bf16 = 4 MB
static const size_t OFF_X2   = 4u * 1024 * 1024;             // 8192 f32
static const size_t OFF_AP   = OFF_X2 + (size_t)TWO_N * 4;   // 4096 f32
static const size_t OFF_FLAG = OFF_AP + (size_t)NHALF * 4;   // 1 int (padded)
static const size_t OFF_PART = OFF_FLAG + 256;               // 64 * 8192 f32 = 2 MB
static const size_t OFF_RS   = OFF_PART + 64ull * TWO_N * 4; // 8192 f32

typedef __attribute__((ext_vector_type(8))) short bf16x8;
typedef __attribute__((ext_vector_type(4))) float f32x4;

__device__ inline ushort f2bf(float f) {
  uint32_t u = __float_as_uint(f);
  uint32_t r = (u + 0x7FFFu + ((u >> 16) & 1u)) >> 16;  // RNE
  return (ushort)r;
}
__device__ inline float bf2f(ushort h) { return __uint_as_float((uint32_t)h << 16); }

// async global->LDS, 16B per lane; LDS dest = wave-uniform base + lane*16
__device__ inline void gload_lds16(const void* g, void* l) {
  __builtin_amdgcn_global_load_lds(
      (const __attribute__((address_space(1))) uint32_t*)(uintptr_t)g,
      (__attribute__((address_space(3))) uint32_t*)(uint32_t)(uintptr_t)l,
      16, 0, 0);
}

// ---------------- prep: bf16 convert + x2 (from bf16 values) + mask-dtype detect ----------------
__global__ __launch_bounds__(256) void smv2_prep(
    const float* __restrict__ emb,
    const uint32_t* __restrict__ maskw,
    ushort* __restrict__ emb_bf,
    float* __restrict__ x2,
    int* __restrict__ flag)
{
  const int t = threadIdx.x;
  if (blockIdx.x == 0) {
    __shared__ int sflag;
    if (t == 0) sflag = 0;
    __syncthreads();
    int found = 0;
    #pragma unroll
    for (int k = 0; k < 8; ++k) {
      uint32_t w = maskw[t * 8 + k];
      // bytes all in {0,1} and value > 1  => 1-byte-per-element mask
      if (w > 1u && (w & 0xFEFEFEFEu) == 0u) found = 1;
    }
    if (found) atomicOr(&sflag, 1);
    __syncthreads();
    if (t == 0) *flag = sflag;
  }
  const int row  = blockIdx.x * 8 + (t >> 5);
  const int lane = t & 31;
  const float* rp = emb + (size_t)row * DDIM + lane * 8;
  float4 v0 = *(const float4*)(rp);
  float4 v1 = *(const float4*)(rp + 4);
  float vals[8] = {v0.x, v0.y, v0.z, v0.w, v1.x, v1.y, v1.z, v1.w};
  uint32_t packed[4];
  float ss = 0.f;
  #pragma unroll
  for (int k = 0; k < 4; ++k) {
    ushort h0 = f2bf(vals[2 * k]);
    ushort h1 = f2bf(vals[2 * k + 1]);
    packed[k] = (uint32_t)h0 | ((uint32_t)h1 << 16);
    float f0 = bf2f(h0), f1 = bf2f(h1);
    ss += f0 * f0 + f1 * f1;
  }
  *(uint4*)(emb_bf + (size_t)row * DDIM + lane * 8) =
      make_uint4(packed[0], packed[1], packed[2], packed[3]);
  #pragma unroll
  for (int m = 1; m < 32; m <<= 1) ss += __shfl_xor(ss, m);
  if (lane == 0) x2[row] = ss;
}

// ---------------- main: fused Gram -> distance -> exp -> masked row partials ----------------
// 512 threads (8 waves, 2x4 wave grid), tile 128x128, K split in 2x128.
// LDS: A 32KB + B 32KB + mask 16KB = 80KB -> 2 blocks/CU, 4 waves/SIMD.
__global__ __launch_bounds__(512, 4) void smv2_main(
    const ushort* __restrict__ emb_bf,
    const float* __restrict__ x2,
    const uint8_t* __restrict__ mask8,
    const int* __restrict__ flagp,
    float* __restrict__ ap,
    float* __restrict__ partial)
{
  __shared__ char ldsA[128 * 256];
  __shared__ char ldsB[128 * 256];
  __shared__ uint8_t ldsM[128 * 128];

  const int t  = threadIdx.x;
  const int bx = blockIdx.x;
  const int by = blockIdx.y;
  const int brow = by * 128;
  const int bcol = bx * 128;

  const char* gA = (const char*)(emb_bf + (size_t)brow * DDIM);  // 512B rows
  const char* gB = (const char*)(emb_bf + (size_t)bcol * DDIM);

  // ---- stage mask tile (16KB), row-swizzled by ((row>>2)&3)<<5 ----
  #pragma unroll
  for (int it = 0; it < 2; ++it) {
    const int dl   = it * 8192 + t * 16;
    const int mrow = dl >> 7;
    const int mc   = dl & 127;
    const int msw  = ((mrow >> 2) & 3) << 5;
    gload_lds16(mask8 + (size_t)(brow + mrow) * TWO_N + bcol + (mc ^ msw), ldsM + dl);
  }

  const int w  = t >> 6;
  const int l  = t & 63;
  const int wr = w >> 2;           // wave row 0..1  (64 rows)
  const int wc = w & 3;            // wave col 0..3  (32 cols)
  const int cl = l & 15;
  const int kh = l >> 4;
  const int swz = (cl & 7) << 4;

  f32x4 acc[4][2];
  #pragma unroll
  for (int m = 0; m < 4; ++m)
    #pragma unroll
    for (int n = 0; n < 2; ++n) {
      f32x4 z = {0.f, 0.f, 0.f, 0.f};
      acc[m][n] = z;
    }

  // ---- two K halves: stage 32KB A + 32KB B (256B rows, XOR-swizzled), then MFMA ----
  #pragma unroll
  for (int h = 0; h < 2; ++h) {
    #pragma unroll
    for (int it = 0; it < 4; ++it) {
      const int dl  = it * 8192 + t * 16;
      const int row = dl >> 8;
      const int c   = dl & 255;
      const int cb  = c ^ ((row & 7) << 4);
      gload_lds16(gA + (size_t)row * 512 + h * 256 + cb, ldsA + dl);
      gload_lds16(gB + (size_t)row * 512 + h * 256 + cb, ldsB + dl);
    }
    __syncthreads();  // vmcnt drained by compiler before barrier

    #pragma unroll
    for (int ks = 0; ks < 4; ++ks) {
      const int kb = ks * 64 + kh * 16;
      bf16x8 a[4], b[2];
      #pragma unroll
      for (int m = 0; m < 4; ++m)
        a[m] = *(const bf16x8*)(ldsA + (wr * 64 + m * 16 + cl) * 256 + (kb ^ swz));
      #pragma unroll
      for (int n = 0; n < 2; ++n)
        b[n] = *(const bf16x8*)(ldsB + (wc * 32 + n * 16 + cl) * 256 + (kb ^ swz));
      #pragma unroll
      for (int m = 0; m < 4; ++m)
        #pragma unroll
        for (int n = 0; n < 2; ++n)
          acc[m][n] = __builtin_amdgcn_mfma_f32_16x16x32_bf16(a[m], b[n], acc[m][n], 0, 0, 0);
    }
    __syncthreads();  // all reads done before overwrite / before part reuse
  }

  float* part = (float*)ldsA;  // [4][128] row partials (ldsA free now)
  const int isByte = *flagp;
  const uint32_t* maskww = (const uint32_t*)mask8;

  float x2j[2];
  #pragma unroll
  for (int n = 0; n < 2; ++n) x2j[n] = x2[bcol + wc * 32 + n * 16 + cl];

  #pragma unroll
  for (int m = 0; m < 4; ++m) {
    #pragma unroll
    for (int q = 0; q < 4; ++q) {
      const int lrow = wr * 64 + m * 16 + kh * 4 + q;  // C/D: row = (l>>4)*4 + reg
      const int gi = brow + lrow;
      const float xi = x2[gi];
      const int msw = ((lrow >> 2) & 3) << 5;
      float rp = 0.f;
      #pragma unroll
      for (int n = 0; n < 2; ++n) {
        const int jc = wc * 32 + n * 16 + cl;
        const int gj = bcol + jc;
        const float g = acc[m][n][q];
        float sq = (gi == gj) ? 0.f : (xi + x2j[n] - 2.f * g);
        sq = fmaxf(sq, 0.f) + 1e-12f;
        const float dd = sqrtf(sq);
        if (gj == gi + NHALF && gi < NHALF) ap[gi] = dd;  // anchor-positive distance
        bool mk;
        if (isByte) mk = ldsM[lrow * 128 + (jc ^ msw)] != 0;
        else        mk = maskww[(size_t)gi * TWO_N + gj] != 0u;
        rp += mk ? __expf(MARGIN - dd) : 0.f;
      }
      #pragma unroll
      for (int s = 1; s < 16; s <<= 1) rp += __shfl_xor(rp, s);
      if (cl == 0) part[wc * 128 + lrow] = rp;
    }
  }
  __syncthreads();
  if (t < 128) {
    partial[(size_t)bx * TWO_N + brow + t] =
        (part[t] + part[128 + t]) + (part[256 + t] + part[384 + t]);
  }
}

// ---------------- row sums: rs[i] = sum over 64 col-tiles ----------------
__global__ __launch_bounds__(256) void smv2_rowsum(
    const float* __restrict__ partial, float* __restrict__ rs)
{
  const int row = blockIdx.x * 256 + threadIdx.x;
  float s = 0.f;
  #pragma unroll 8
  for (int b = 0; b < 64; ++b) s += partial[(size_t)b * TWO_N + row];
  rs[row] = s;
}

// ---------------- finalize: j = log(rs[i]+rs[i+N]) + ap[i]; loss ----------------
__global__ __launch_bounds__(1024) void smv2_finalize(
    const float* __restrict__ rs, const float* __restrict__ ap,
    float* __restrict__ out)
{
  const int t = threadIdx.x;
  float sum = 0.f, cnt = 0.f;
  for (int i = t; i < NHALF; i += 1024) {
    float rsum = rs[i] + rs[i + NHALF];
    float jv = logf(rsum) + ap[i];
    if (!isnan(jv)) {
      cnt += 1.f;
      float mj = fmaxf(jv, 0.f);
      sum += mj * mj;
    }
  }
  __shared__ float ssum[16], scnt[16];
  #pragma unroll
  for (int s = 32; s >= 1; s >>= 1) {
    sum += __shfl_down(sum, s);
    cnt += __shfl_down(cnt, s);
  }
  const int wid = t >> 6, lid = t & 63;
  if (lid == 0) { ssum[wid] = sum; scnt[wid] = cnt; }
  __syncthreads();
  if (t == 0) {
    float S = 0.f, C = 0.f;
    #pragma unroll
    for (int i = 0; i < 16; ++i) { S += ssum[i]; C += scnt[i]; }
    if (C < 1.f) C = 1.f;
    out[0] = S / C * 0.5f;
  }
}

extern "C" void kernel_launch(void* const* d_in, const int* in_sizes, int n_in,
                              void* d_out, int out_size, void* d_ws, size_t ws_size,
                              hipStream_t stream) {
  const float* emb = (const float*)d_in[0];
  const void* mask = d_in[1];
  char* ws = (char*)d_ws;

  ushort* emb_bf = (ushort*)(ws + OFF_EMB);
  float*  x2     = (float*)(ws + OFF_X2);
  float*  ap     = (float*)(ws + OFF_AP);
  int*    flag   = (int*)(ws + OFF_FLAG);
  float*  part   = (float*)(ws + OFF_PART);
  float*  rs     = (float*)(ws + OFF_RS);

  smv2_prep<<<1024, 256, 0, stream>>>(emb, (const uint32_t*)mask, emb_bf, x2, flag);
  dim3 grid(64, 64);
  smv2_main<<<grid, 512, 0, stream>>>(emb_bf, x2, (const uint8_t*)mask, flag, ap, part);
  smv2_rowsum<<<32, 256, 0, stream>>>(part, rs);
  smv2_finalize<<<1, 1024, 0, stream>>>(rs, ap, (float*)d_out);
}

// Round 3
// 513.632 us; speedup vs baseline: 1.5351x; 1.0071x over previous
//
#include <hip/hip_runtime.h>
#include <hip/hip_bf16.h>
#include <stdint.h>

#define TWO_N  8192
#define NHALF  4096
#define DDIM   256
#define MARGIN 0.5f

// ---- workspace layout (bytes) ----
static const size_t OFF_EMB  = 0;                            // 8192*256 bf16 = 4 MB
static const size_t OFF_X2   = 4u * 1024 * 1024;             // 8192 f32
static const size_t OFF_AP   = OFF_X2 + (size_t)TWO_N * 4;   // 4096 f32
static const size_t OFF_FLAG = OFF_AP + (size_t)NHALF * 4;   // 1 int (padded)
static const size_t OFF_PART = OFF_FLAG + 256;               // 64 * 8192 f32 = 2 MB
static const size_t OFF_RS   = OFF_PART + 64ull * TWO_N * 4; // 8192 f32

typedef __attribute__((ext_vector_type(8))) short bf16x8;
typedef __attribute__((ext_vector_type(4))) float f32x4;

__device__ inline ushort f2bf(float f) {
  uint32_t u = __float_as_uint(f);
  uint32_t r = (u + 0x7FFFu + ((u >> 16) & 1u)) >> 16;  // RNE
  return (ushort)r;
}
__device__ inline float bf2f(ushort h) { return __uint_as_float((uint32_t)h << 16); }

// async global->LDS, 16B per lane; LDS dest = wave-uniform base + lane*16
__device__ inline void gload_lds16(const void* g, void* l) {
  __builtin_amdgcn_global_load_lds(
      (const __attribute__((address_space(1))) uint32_t*)(uintptr_t)g,
      (__attribute__((address_space(3))) uint32_t*)(uint32_t)(uintptr_t)l,
      16, 0, 0);
}

// ---------------- prep: bf16 convert + x2 (from bf16 values) + mask-dtype detect ----------------
__global__ __launch_bounds__(256) void smv2_prep(
    const float* __restrict__ emb,
    const uint32_t* __restrict__ maskw,
    ushort* __restrict__ emb_bf,
    float* __restrict__ x2,
    int* __restrict__ flag)
{
  const int t = threadIdx.x;
  if (blockIdx.x == 0) {
    __shared__ int sflag;
    if (t == 0) sflag = 0;
    __syncthreads();
    int found = 0;
    #pragma unroll
    for (int k = 0; k < 8; ++k) {
      uint32_t w = maskw[t * 8 + k];
      // bytes all in {0,1} and value > 1  => 1-byte-per-element mask
      if (w > 1u && (w & 0xFEFEFEFEu) == 0u) found = 1;
    }
    if (found) atomicOr(&sflag, 1);
    __syncthreads();
    if (t == 0) *flag = sflag;
  }
  const int row  = blockIdx.x * 8 + (t >> 5);
  const int lane = t & 31;
  const float* rp = emb + (size_t)row * DDIM + lane * 8;
  float4 v0 = *(const float4*)(rp);
  float4 v1 = *(const float4*)(rp + 4);
  float vals[8] = {v0.x, v0.y, v0.z, v0.w, v1.x, v1.y, v1.z, v1.w};
  uint32_t packed[4];
  float ss = 0.f;
  #pragma unroll
  for (int k = 0; k < 4; ++k) {
    ushort h0 = f2bf(vals[2 * k]);
    ushort h1 = f2bf(vals[2 * k + 1]);
    packed[k] = (uint32_t)h0 | ((uint32_t)h1 << 16);
    float f0 = bf2f(h0), f1 = bf2f(h1);
    ss += f0 * f0 + f1 * f1;
  }
  *(uint4*)(emb_bf + (size_t)row * DDIM + lane * 8) =
      make_uint4(packed[0], packed[1], packed[2], packed[3]);
  #pragma unroll
  for (int m = 1; m < 32; m <<= 1) ss += __shfl_xor(ss, m);
  if (lane == 0) x2[row] = ss;
}

// ---------------- main: fused Gram -> distance -> exp -> masked row partials ----------------
// 512 threads (8 waves, 2x4), tile 128x128, K split 4x64, double-buffered A/B LDS.
// LDS: 2 x (A 16KB + B 16KB) + mask 16KB = 80KB -> 2 blocks/CU.
// Pipeline: stage(p+1) issued BEFORE compute(p); one vmcnt-drain barrier per phase.
__global__ __launch_bounds__(512, 4) void smv2_main(
    const ushort* __restrict__ emb_bf,
    const float* __restrict__ x2,
    const uint8_t* __restrict__ mask8,
    const int* __restrict__ flagp,
    float* __restrict__ ap,
    float* __restrict__ partial)
{
  __shared__ char ldsAB[2][32768];   // [buf][A 16KB | B 16KB]
  __shared__ uint8_t ldsM[128 * 128];

  const int t = threadIdx.x;

  // XCD-aware remap: each XCD owns an 8-wide bx stripe, sweeps by.
  // bid = by*64 + bxl*8 + xcd  (bijective)
  const int bid = blockIdx.x;
  const int xcd = bid & 7;
  const int idx = bid >> 3;
  const int bx  = xcd * 8 + (idx & 7);
  const int by  = idx >> 3;
  const int brow = by * 128;
  const int bcol = bx * 128;

  const char* gA = (const char*)(emb_bf + (size_t)brow * DDIM);  // 512B rows
  const char* gB = (const char*)(emb_bf + (size_t)bcol * DDIM);

  // ---- stage mask tile (16KB), row-swizzled by ((row>>2)&3)<<5 ----
  #pragma unroll
  for (int it = 0; it < 2; ++it) {
    const int dl   = it * 8192 + t * 16;
    const int mrow = dl >> 7;
    const int mc   = dl & 127;
    const int msw  = ((mrow >> 2) & 3) << 5;
    gload_lds16(mask8 + (size_t)(brow + mrow) * TWO_N + bcol + (mc ^ msw), ldsM + dl);
  }

  // ---- stage phase 0 (A/B 128x64 bf16 each = 16KB+16KB, XOR-swizzled rows) ----
  #pragma unroll
  for (int it = 0; it < 2; ++it) {
    const int dl  = it * 8192 + t * 16;
    const int row = dl >> 7;       // 0..127
    const int c   = dl & 127;
    const int cb  = c ^ ((row & 7) << 4);
    gload_lds16(gA + (size_t)row * 512 + 0 * 128 + cb, ldsAB[0] + dl);
    gload_lds16(gB + (size_t)row * 512 + 0 * 128 + cb, ldsAB[0] + 16384 + dl);
  }
  __syncthreads();  // fill barrier: drains mask + phase-0 loads

  const int w  = t >> 6;
  const int l  = t & 63;
  const int wr = w >> 2;           // wave row 0..1  (64 rows)
  const int wc = w & 3;            // wave col 0..3  (32 cols)
  const int cl = l & 15;
  const int kh = l >> 4;
  const int swz = (cl & 7) << 4;

  f32x4 acc[4][2];
  #pragma unroll
  for (int m = 0; m < 4; ++m)
    #pragma unroll
    for (int n = 0; n < 2; ++n) {
      f32x4 z = {0.f, 0.f, 0.f, 0.f};
      acc[m][n] = z;
    }

  #pragma unroll
  for (int p = 0; p < 4; ++p) {
    // issue next-phase staging into the other buffer (async, overlaps compute)
    if (p < 3) {
      char* dst = ldsAB[(p + 1) & 1];
      #pragma unroll
      for (int it = 0; it < 2; ++it) {
        const int dl  = it * 8192 + t * 16;
        const int row = dl >> 7;
        const int c   = dl & 127;
        const int cb  = c ^ ((row & 7) << 4);
        gload_lds16(gA + (size_t)row * 512 + (p + 1) * 128 + cb, dst + dl);
        gload_lds16(gB + (size_t)row * 512 + (p + 1) * 128 + cb, dst + 16384 + dl);
      }
    }
    __builtin_amdgcn_sched_barrier(0);  // pin: stage issued before compute

    const char* buf = ldsAB[p & 1];
    #pragma unroll
    for (int ks = 0; ks < 2; ++ks) {
      const int kb = ks * 64 + kh * 16;   // byte offset in 128B row
      bf16x8 a[4], b[2];
      #pragma unroll
      for (int m = 0; m < 4; ++m)
        a[m] = *(const bf16x8*)(buf + (wr * 64 + m * 16 + cl) * 128 + (kb ^ swz));
      #pragma unroll
      for (int n = 0; n < 2; ++n)
        b[n] = *(const bf16x8*)(buf + 16384 + (wc * 32 + n * 16 + cl) * 128 + (kb ^ swz));
      #pragma unroll
      for (int m = 0; m < 4; ++m)
        #pragma unroll
        for (int n = 0; n < 2; ++n)
          acc[m][n] = __builtin_amdgcn_mfma_f32_16x16x32_bf16(a[m], b[n], acc[m][n], 0, 0, 0);
    }
    // drain next-phase loads AFTER compute (they had the whole phase to land)
    __syncthreads();
  }

  float* part = (float*)ldsAB[0];  // [4][128] row partials (buffers free now)
  const int isByte = *flagp;
  const uint32_t* maskww = (const uint32_t*)mask8;

  float x2j[2];
  #pragma unroll
  for (int n = 0; n < 2; ++n) x2j[n] = x2[bcol + wc * 32 + n * 16 + cl];

  #pragma unroll
  for (int m = 0; m < 4; ++m) {
    #pragma unroll
    for (int q = 0; q < 4; ++q) {
      const int lrow = wr * 64 + m * 16 + kh * 4 + q;  // C/D: row = (l>>4)*4 + reg
      const int gi = brow + lrow;
      const float xi = x2[gi];
      const int msw = ((lrow >> 2) & 3) << 5;
      float rp = 0.f;
      #pragma unroll
      for (int n = 0; n < 2; ++n) {
        const int jc = wc * 32 + n * 16 + cl;
        const int gj = bcol + jc;
        const float g = acc[m][n][q];
        float sq = (gi == gj) ? 0.f : (xi + x2j[n] - 2.f * g);
        sq = fmaxf(sq, 0.f) + 1e-12f;
        const float dd = sqrtf(sq);
        if (gj == gi + NHALF && gi < NHALF) ap[gi] = dd;  // anchor-positive distance
        bool mk;
        if (isByte) mk = ldsM[lrow * 128 + (jc ^ msw)] != 0;
        else        mk = maskww[(size_t)gi * TWO_N + gj] != 0u;
        rp += mk ? __expf(MARGIN - dd) : 0.f;
      }
      #pragma unroll
      for (int s = 1; s < 16; s <<= 1) rp += __shfl_xor(rp, s);
      if (cl == 0) part[wc * 128 + lrow] = rp;
    }
  }
  __syncthreads();
  if (t < 128) {
    partial[(size_t)bx * TWO_N + brow + t] =
        (part[t] + part[128 + t]) + (part[256 + t] + part[384 + t]);
  }
}

// ---------------- row sums: rs[i] = sum over 64 col-tiles ----------------
__global__ __launch_bounds__(256) void smv2_rowsum(
    const float* __restrict__ partial, float* __restrict__ rs)
{
  const int row = blockIdx.x * 256 + threadIdx.x;
  float s = 0.f;
  #pragma unroll 8
  for (int b = 0; b < 64; ++b) s += partial[(size_t)b * TWO_N + row];
  rs[row] = s;
}

// ---------------- finalize: j = log(rs[i]+rs[i+N]) + ap[i]; loss ----------------
__global__ __launch_bounds__(1024) void smv2_finalize(
    const float* __restrict__ rs, const float* __restrict__ ap,
    float* __restrict__ out)
{
  const int t = threadIdx.x;
  float sum = 0.f, cnt = 0.f;
  for (int i = t; i < NHALF; i += 1024) {
    float rsum = rs[i] + rs[i + NHALF];
    float jv = logf(rsum) + ap[i];
    if (!isnan(jv)) {
      cnt += 1.f;
      float mj = fmaxf(jv, 0.f);
      sum += mj * mj;
    }
  }
  __shared__ float ssum[16], scnt[16];
  #pragma unroll
  for (int s = 32; s >= 1; s >>= 1) {
    sum += __shfl_down(sum, s);
    cnt += __shfl_down(cnt, s);
  }
  const int wid = t >> 6, lid = t & 63;
  if (lid == 0) { ssum[wid] = sum; scnt[wid] = cnt; }
  __syncthreads();
  if (t == 0) {
    float S = 0.f, C = 0.f;
    #pragma unroll
    for (int i = 0; i < 16; ++i) { S += ssum[i]; C += scnt[i]; }
    if (C < 1.f) C = 1.f;
    out[0] = S / C * 0.5f;
  }
}

extern "C" void kernel_launch(void* const* d_in, const int* in_sizes, int n_in,
                              void* d_out, int out_size, void* d_ws, size_t ws_size,
                              hipStream_t stream) {
  const float* emb = (const float*)d_in[0];
  const void* mask = d_in[1];
  char* ws = (char*)d_ws;

  ushort* emb_bf = (ushort*)(ws + OFF_EMB);
  float*  x2     = (float*)(ws + OFF_X2);
  float*  ap     = (float*)(ws + OFF_AP);
  int*    flag   = (int*)(ws + OFF_FLAG);
  float*  part   = (float*)(ws + OFF_PART);
  float*  rs     = (float*)(ws + OFF_RS);

  smv2_prep<<<1024, 256, 0, stream>>>(emb, (const uint32_t*)mask, emb_bf, x2, flag);
  smv2_main<<<4096, 512, 0, stream>>>(emb_bf, x2, (const uint8_t*)mask, flag, ap, part);
  smv2_rowsum<<<32, 256, 0, stream>>>(part, rs);
  smv2_finalize<<<1, 1024, 0, stream>>>(rs, ap, (float*)d_out);
}

// Round 4
// 455.609 us; speedup vs baseline: 1.7306x; 1.1274x over previous
//
#include <hip/hip_runtime.h>
#include <hip/hip_bf16.h>
#include <stdint.h>

#define TWO_N  8192
#define NHALF  4096
#define DDIM   256
#define MARGIN 0.5f
#define NTRI   2080   // 64*65/2 upper-triangle tile pairs

// ---- workspace layout (bytes) ----
static const size_t OFF_EMB  = 0;                            // 8192*256 bf16 = 4 MB
static const size_t OFF_X2   = 4u * 1024 * 1024;             // 8192 f32
static const size_t OFF_AP   = OFF_X2 + (size_t)TWO_N * 4;   // 4096 f32
static const size_t OFF_FLAG = OFF_AP + (size_t)NHALF * 4;   // 1 int (padded)
static const size_t OFF_PART = OFF_FLAG + 256;               // 64 * 8192 f32 = 2 MB
static const size_t OFF_RS   = OFF_PART + 64ull * TWO_N * 4; // 8192 f32

typedef __attribute__((ext_vector_type(8))) short bf16x8;
typedef __attribute__((ext_vector_type(4))) float f32x4;

__device__ inline ushort f2bf(float f) {
  uint32_t u = __float_as_uint(f);
  uint32_t r = (u + 0x7FFFu + ((u >> 16) & 1u)) >> 16;  // RNE
  return (ushort)r;
}
__device__ inline float bf2f(ushort h) { return __uint_as_float((uint32_t)h << 16); }

// async global->LDS, 16B per lane; LDS dest = wave-uniform base + lane*16
__device__ inline void gload_lds16(const void* g, void* l) {
  __builtin_amdgcn_global_load_lds(
      (const __attribute__((address_space(1))) uint32_t*)(uintptr_t)g,
      (__attribute__((address_space(3))) uint32_t*)(uint32_t)(uintptr_t)l,
      16, 0, 0);
}

// ---------------- prep: bf16 convert + x2 (from bf16 values) + mask-dtype detect ----------------
__global__ __launch_bounds__(256) void smv2_prep(
    const float* __restrict__ emb,
    const uint32_t* __restrict__ maskw,
    ushort* __restrict__ emb_bf,
    float* __restrict__ x2,
    int* __restrict__ flag)
{
  const int t = threadIdx.x;
  if (blockIdx.x == 0) {
    __shared__ int sflag;
    if (t == 0) sflag = 0;
    __syncthreads();
    int found = 0;
    #pragma unroll
    for (int k = 0; k < 8; ++k) {
      uint32_t w = maskw[t * 8 + k];
      // bytes all in {0,1} and value > 1  => 1-byte-per-element mask
      if (w > 1u && (w & 0xFEFEFEFEu) == 0u) found = 1;
    }
    if (found) atomicOr(&sflag, 1);
    __syncthreads();
    if (t == 0) *flag = sflag;
  }
  const int row  = blockIdx.x * 8 + (t >> 5);
  const int lane = t & 31;
  const float* rp = emb + (size_t)row * DDIM + lane * 8;
  float4 v0 = *(const float4*)(rp);
  float4 v1 = *(const float4*)(rp + 4);
  float vals[8] = {v0.x, v0.y, v0.z, v0.w, v1.x, v1.y, v1.z, v1.w};
  uint32_t packed[4];
  float ss = 0.f;
  #pragma unroll
  for (int k = 0; k < 4; ++k) {
    ushort h0 = f2bf(vals[2 * k]);
    ushort h1 = f2bf(vals[2 * k + 1]);
    packed[k] = (uint32_t)h0 | ((uint32_t)h1 << 16);
    float f0 = bf2f(h0), f1 = bf2f(h1);
    ss += f0 * f0 + f1 * f1;
  }
  *(uint4*)(emb_bf + (size_t)row * DDIM + lane * 8) =
      make_uint4(packed[0], packed[1], packed[2], packed[3]);
  #pragma unroll
  for (int m = 1; m < 32; m <<= 1) ss += __shfl_xor(ss, m);
  if (lane == 0) x2[row] = ss;
}

// ---------------- main: symmetric fused Gram -> dist -> exp -> masked row+col partials ----------
// Upper-triangle tile pairs (by<=bx), 512 threads (8 waves 2x4), tile 128x128, K phases 4x64.
// LDS: A 16K + B 16K + M1 16K + x2 1K = 49KB -> 3 blocks/CU.
// Off-diagonal blocks also emit the mirrored (col-side) row sums reusing the same exp values.
__global__ __launch_bounds__(512, 6) void smv2_main(
    const ushort* __restrict__ emb_bf,
    const float* __restrict__ x2,
    const uint8_t* __restrict__ mask8,
    const int* __restrict__ flagp,
    float* __restrict__ ap,
    float* __restrict__ partial)
{
  __shared__ char ldsA[128 * 128];     // 16 KB  A K-phase tile
  __shared__ char ldsB[128 * 128];     // 16 KB  B K-phase tile
  __shared__ uint8_t ldsM[128 * 128];  // 16 KB  mask M1 (row-side)
  __shared__ float ldsX[256];          // x2[brow..+128) | x2[bcol..+128)

  const int t = threadIdx.x;

  // XCD chunking (2080 = 8*260) + triangular decode, bx-outer so consecutive
  // blocks on one XCD share the B panel (bcol).
  const int bid = blockIdx.x;
  const int idx = (bid & 7) * (NTRI / 8) + (bid >> 3);
  float rf = sqrtf(8.f * (float)idx + 1.f);
  int bx = (int)((rf - 1.f) * 0.5f);
  while ((bx + 1) * (bx + 2) / 2 <= idx) ++bx;
  while (bx * (bx + 1) / 2 > idx) --bx;
  const int by = idx - bx * (bx + 1) / 2;  // by <= bx
  const int brow = by * 128;
  const int bcol = bx * 128;
  const bool diag = (bx == by);

  const char* gA = (const char*)(emb_bf + (size_t)brow * DDIM);  // 512B rows
  const char* gB = (const char*)(emb_bf + (size_t)bcol * DDIM);

  // ---- stage M1 mask tile (16KB), row-swizzled by kh-group ----
  #pragma unroll
  for (int it = 0; it < 2; ++it) {
    const int dl   = it * 8192 + t * 16;
    const int mrow = dl >> 7;
    const int mc   = dl & 127;
    const int msw  = ((mrow >> 2) & 3) << 5;
    gload_lds16(mask8 + (size_t)(brow + mrow) * TWO_N + bcol + (mc ^ msw), ldsM + dl);
  }
  // ---- stage x2 slices (1KB via one wave) ----
  if (t < 64) {
    const float* src = (t < 32) ? (x2 + brow + t * 4) : (x2 + bcol + (t - 32) * 4);
    gload_lds16(src, (char*)ldsX + t * 16);
  }
  // ---- stage K-phase 0 ----
  #pragma unroll
  for (int it = 0; it < 2; ++it) {
    const int dl  = it * 8192 + t * 16;
    const int row = dl >> 7;
    const int c   = dl & 127;
    const int cb  = c ^ ((row & 7) << 4);
    gload_lds16(gA + (size_t)row * 512 + cb, ldsA + dl);
    gload_lds16(gB + (size_t)row * 512 + cb, ldsB + dl);
  }
  __syncthreads();

  const int w  = t >> 6;
  const int l  = t & 63;
  const int wr = w >> 2;           // wave row 0..1  (64 rows)
  const int wc = w & 3;            // wave col 0..3  (32 cols)
  const int cl = l & 15;
  const int kh = l >> 4;
  const int swz = (cl & 7) << 4;

  f32x4 acc[4][2];
  #pragma unroll
  for (int m = 0; m < 4; ++m)
    #pragma unroll
    for (int n = 0; n < 2; ++n) {
      f32x4 z = {0.f, 0.f, 0.f, 0.f};
      acc[m][n] = z;
    }

  #pragma unroll
  for (int p = 0; p < 4; ++p) {
    #pragma unroll
    for (int ks = 0; ks < 2; ++ks) {
      const int kb = ks * 64 + kh * 16;
      bf16x8 a[4], b[2];
      #pragma unroll
      for (int m = 0; m < 4; ++m)
        a[m] = *(const bf16x8*)(ldsA + (wr * 64 + m * 16 + cl) * 128 + (kb ^ swz));
      #pragma unroll
      for (int n = 0; n < 2; ++n)
        b[n] = *(const bf16x8*)(ldsB + (wc * 32 + n * 16 + cl) * 128 + (kb ^ swz));
      #pragma unroll
      for (int m = 0; m < 4; ++m)
        #pragma unroll
        for (int n = 0; n < 2; ++n)
          acc[m][n] = __builtin_amdgcn_mfma_f32_16x16x32_bf16(a[m], b[n], acc[m][n], 0, 0, 0);
    }
    __syncthreads();                 // all reads of this phase done
    if (p < 3) {
      #pragma unroll
      for (int it = 0; it < 2; ++it) {
        const int dl  = it * 8192 + t * 16;
        const int row = dl >> 7;
        const int c   = dl & 127;
        const int cb  = c ^ ((row & 7) << 4);
        gload_lds16(gA + (size_t)row * 512 + (p + 1) * 128 + cb, ldsA + dl);
        gload_lds16(gB + (size_t)row * 512 + (p + 1) * 128 + cb, ldsB + dl);
      }
      __syncthreads();               // next phase staged
    }
  }

  const int isByte = *flagp;
  const uint32_t* maskww = (const uint32_t*)mask8;

  // ---- prefetch col-side (M2) mask words: mask[gj][gi] packed 4 rows/u32 ----
  uint32_t m2r[2][4];
  if (!diag && isByte) {
    #pragma unroll
    for (int n = 0; n < 2; ++n) {
      const int gj = bcol + wc * 32 + n * 16 + cl;
      #pragma unroll
      for (int m = 0; m < 4; ++m)
        m2r[n][m] = *(const uint32_t*)(mask8 + (size_t)gj * TWO_N + brow + wr * 64 + m * 16 + kh * 4);
    }
  }

  float* part  = (float*)ldsA;  // [4][128] row-side partials
  float* part2 = (float*)ldsB;  // [2][128] col-side partials
  float cs[2] = {0.f, 0.f};

  #pragma unroll
  for (int m = 0; m < 4; ++m) {
    #pragma unroll
    for (int q = 0; q < 4; ++q) {
      const int lrow = wr * 64 + m * 16 + kh * 4 + q;  // C/D: row = (l>>4)*4 + reg
      const int gi = brow + lrow;
      const float xi = ldsX[lrow];
      const int msw = kh << 5;       // ((lrow>>2)&3)<<5 == kh<<5
      float rp = 0.f;
      #pragma unroll
      for (int n = 0; n < 2; ++n) {
        const int jc = wc * 32 + n * 16 + cl;
        const int gj = bcol + jc;
        const float g = acc[m][n][q];
        float sq = (gi == gj) ? 0.f : (xi + ldsX[128 + jc] - 2.f * g);
        sq = fmaxf(sq, 0.f) + 1e-12f;
        const float dd = sqrtf(sq);
        if (gj == gi + NHALF && gi < NHALF) ap[gi] = dd;  // anchor-positive distance
        const float e = __expf(MARGIN - dd);
        bool mk1;
        if (isByte) mk1 = ldsM[lrow * 128 + (jc ^ msw)] != 0;
        else        mk1 = maskww[(size_t)gi * TWO_N + gj] != 0u;
        rp += mk1 ? e : 0.f;
        if (!diag) {
          bool mk2;
          if (isByte) mk2 = ((m2r[n][m] >> (8 * q)) & 255u) != 0u;
          else        mk2 = maskww[(size_t)gj * TWO_N + gi] != 0u;
          cs[n] += mk2 ? e : 0.f;
        }
      }
      #pragma unroll
      for (int s = 1; s < 16; s <<= 1) rp += __shfl_xor(rp, s);
      if (cl == 0) part[wc * 128 + lrow] = rp;
    }
  }

  if (!diag) {
    #pragma unroll
    for (int n = 0; n < 2; ++n) {
      cs[n] += __shfl_xor(cs[n], 16);   // reduce over kh
      cs[n] += __shfl_xor(cs[n], 32);
      if (l < 16) part2[wr * 128 + wc * 32 + n * 16 + l] = cs[n];
    }
  }
  __syncthreads();

  if (t < 128) {
    partial[(size_t)bx * TWO_N + brow + t] =
        (part[t] + part[128 + t]) + (part[256 + t] + part[384 + t]);
    if (!diag)
      partial[(size_t)by * TWO_N + bcol + t] = part2[t] + part2[128 + t];
  }
}

// ---------------- row sums: rs[i] = sum over 64 col-tiles ----------------
__global__ __launch_bounds__(256) void smv2_rowsum(
    const float* __restrict__ partial, float* __restrict__ rs)
{
  const int row = blockIdx.x * 256 + threadIdx.x;
  float s = 0.f;
  #pragma unroll 8
  for (int b = 0; b < 64; ++b) s += partial[(size_t)b * TWO_N + row];
  rs[row] = s;
}

// ---------------- finalize: j = log(rs[i]+rs[i+N]) + ap[i]; loss ----------------
__global__ __launch_bounds__(1024) void smv2_finalize(
    const float* __restrict__ rs, const float* __restrict__ ap,
    float* __restrict__ out)
{
  const int t = threadIdx.x;
  float sum = 0.f, cnt = 0.f;
  for (int i = t; i < NHALF; i += 1024) {
    float rsum = rs[i] + rs[i + NHALF];
    float jv = logf(rsum) + ap[i];
    if (!isnan(jv)) {
      cnt += 1.f;
      float mj = fmaxf(jv, 0.f);
      sum += mj * mj;
    }
  }
  __shared__ float ssum[16], scnt[16];
  #pragma unroll
  for (int s = 32; s >= 1; s >>= 1) {
    sum += __shfl_down(sum, s);
    cnt += __shfl_down(cnt, s);
  }
  const int wid = t >> 6, lid = t & 63;
  if (lid == 0) { ssum[wid] = sum; scnt[wid] = cnt; }
  __syncthreads();
  if (t == 0) {
    float S = 0.f, C = 0.f;
    #pragma unroll
    for (int i = 0; i < 16; ++i) { S += ssum[i]; C += scnt[i]; }
    if (C < 1.f) C = 1.f;
    out[0] = S / C * 0.5f;
  }
}

extern "C" void kernel_launch(void* const* d_in, const int* in_sizes, int n_in,
                              void* d_out, int out_size, void* d_ws, size_t ws_size,
                              hipStream_t stream) {
  const float* emb = (const float*)d_in[0];
  const void* mask = d_in[1];
  char* ws = (char*)d_ws;

  ushort* emb_bf = (ushort*)(ws + OFF_EMB);
  float*  x2     = (float*)(ws + OFF_X2);
  float*  ap     = (float*)(ws + OFF_AP);
  int*    flag   = (int*)(ws + OFF_FLAG);
  float*  part   = (float*)(ws + OFF_PART);
  float*  rs     = (float*)(ws + OFF_RS);

  smv2_prep<<<1024, 256, 0, stream>>>(emb, (const uint32_t*)mask, emb_bf, x2, flag);
  smv2_main<<<NTRI, 512, 0, stream>>>(emb_bf, x2, (const uint8_t*)mask, flag, ap, part);
  smv2_rowsum<<<32, 256, 0, stream>>>(part, rs);
  smv2_finalize<<<1, 1024, 0, stream>>>(rs, ap, (float*)d_out);
}